// Round 16
// baseline (256.049 us; speedup 1.0000x reference)
//
#include <hip/hip_runtime.h>

#define DFEAT 160
#define XROW 192   // padded bf16 x-row: 64 ss + 32*(3 v + 1 pad)

typedef float  f4v __attribute__((ext_vector_type(4)));
typedef short  s8v __attribute__((ext_vector_type(8)));

__device__ __constant__ float kINV3 = 0.57735026918962576451f;  // 1/sqrt(3)
__device__ __constant__ float kINV6 = 0.40824829046386301637f;  // 1/sqrt(6)
__device__ __constant__ float kC0   = 0.10206207261596575f;     // 1/sqrt(96)
__device__ __constant__ float kC1   = 0.15309310892394863f;     // sqrt(3/128)
__device__ __constant__ float kLS   = 0.125f;                   // 1/sqrt(64)
__device__ __constant__ float kLV   = 0.17677669529663687f;     // 1/sqrt(32)

#define WAVE_SYNC() do { \
    asm volatile("s_waitcnt lgkmcnt(0)" ::: "memory"); \
    __builtin_amdgcn_sched_barrier(0); \
} while (0)

#define MFMA(a, b, c) __builtin_amdgcn_mfma_f32_16x16x32_bf16((a), (b), (c), 0, 0, 0)

__device__ __forceinline__ unsigned f2bf(float f) {
    const unsigned u = __builtin_bit_cast(unsigned, f);
    const unsigned r = 0x7fffu + ((u >> 16) & 1u);
    return (u + r) >> 16;
}
__device__ __forceinline__ float bf2f(unsigned short u) {
    return __builtin_bit_cast(float, ((unsigned)u) << 16);
}

// ---------- CSR build (padded segments: deg rounded up to x4) ----------
__global__ void hist_kernel(const int* __restrict__ dst, int* __restrict__ deg, int E) {
    for (int e = blockIdx.x * blockDim.x + threadIdx.x; e < E; e += gridDim.x * blockDim.x)
        atomicAdd(&deg[dst[e]], 1);
}

__global__ __launch_bounds__(256) void blocksum_kernel(const int* __restrict__ deg,
                                                       int* __restrict__ bsum, int N) {
    __shared__ int red[256];
    const int b = blockIdx.x, t = threadIdx.x;
    const int base = b * 1024;
    int s = 0;
    for (int i = t; i < 1024; i += 256) {
        const int idx = base + i;
        if (idx < N) s += (deg[idx] + 3) & ~3;
    }
    red[t] = s;
    __syncthreads();
    for (int off = 128; off > 0; off >>= 1) {
        if (t < off) red[t] += red[t + off];
        __syncthreads();
    }
    if (t == 0) bsum[b] = red[0];
}

__global__ void scanb_kernel(int* __restrict__ bsum, int nb, int* __restrict__ rowptrN) {
    if (threadIdx.x == 0 && blockIdx.x == 0) {
        int run = 0;
        for (int i = 0; i < nb; ++i) { const int v = bsum[i]; bsum[i] = run; run += v; }
        *rowptrN = run;
    }
}

// also writes the <=3 filler slots per node (src=0, sh=0) so no big memsets needed
__global__ __launch_bounds__(256) void scanfinal_kernel(const int* __restrict__ deg,
                                                        const int* __restrict__ bsum,
                                                        int* __restrict__ rowptr,
                                                        int* __restrict__ cursor,
                                                        int* __restrict__ src_sorted,
                                                        float4* __restrict__ sh_sorted,
                                                        int N) {
    __shared__ int ts[256];
    const int b = blockIdx.x, t = threadIdx.x;
    const int i0 = b * 1024 + t * 4;
    int dO[4], dP[4];
    #pragma unroll
    for (int j = 0; j < 4; ++j) {
        dO[j] = (i0 + j < N) ? deg[i0 + j] : 0;
        dP[j] = (dO[j] + 3) & ~3;
    }
    ts[t] = dP[0] + dP[1] + dP[2] + dP[3];
    __syncthreads();
    for (int off = 1; off < 256; off <<= 1) {
        const int v = (t >= off) ? ts[t - off] : 0;
        __syncthreads();
        ts[t] += v;
        __syncthreads();
    }
    int ex = bsum[b] + ((t == 0) ? 0 : ts[t - 1]);
    const float4 z4 = make_float4(0.f, 0.f, 0.f, 0.f);
    #pragma unroll
    for (int j = 0; j < 4; ++j) {
        if (i0 + j < N) {
            rowptr[i0 + j] = ex;
            cursor[i0 + j] = ex;
            for (int f = ex + dO[j]; f < ex + dP[j]; ++f) {
                src_sorted[f] = 0;
                sh_sorted[f] = z4;
            }
            ex += dP[j];
        }
    }
}

// scatter into sorted streams (src + sh)
__global__ void scatter_kernel(const int* __restrict__ src, const int* __restrict__ dst,
                               const float4* __restrict__ sh, int* __restrict__ cursor,
                               int* __restrict__ src_sorted, float4* __restrict__ sh_sorted,
                               int E) {
    for (int e = blockIdx.x * blockDim.x + threadIdx.x; e < E; e += gridDim.x * blockDim.x) {
        const int pos = atomicAdd(&cursor[dst[e]], 1);
        src_sorted[pos] = src[e];
        sh_sorted[pos] = sh[e];
    }
}

// ---------- x -> padded bf16 rows (XROW=192): [0..63]=ss, [64+4u+c]=v[u][c], c=3 pad ----------
__global__ __launch_bounds__(256) void xcast_kernel(const float* __restrict__ x,
                                                    unsigned short* __restrict__ xq,
                                                    int N) {
    const int total = N * 48;  // 48 ushort4 per row
    for (int i = blockIdx.x * 256 + threadIdx.x; i < total; i += gridDim.x * 256) {
        const int n = i / 48, s = i % 48;
        const float* xr = x + (size_t)n * DFEAT;
        ushort4 o;
        if (s < 16) {  // ss block: t = 4s..4s+3
            o.x = (unsigned short)f2bf(xr[4 * s + 0]);
            o.y = (unsigned short)f2bf(xr[4 * s + 1]);
            o.z = (unsigned short)f2bf(xr[4 * s + 2]);
            o.w = (unsigned short)f2bf(xr[4 * s + 3]);
        } else {       // v block: u = s-16
            const int u = s - 16;
            o.x = (unsigned short)f2bf(xr[64 + 3 * u + 0]);
            o.y = (unsigned short)f2bf(xr[64 + 3 * u + 1]);
            o.z = (unsigned short)f2bf(xr[64 + 3 * u + 2]);
            o.w = 0;
        }
        *(ushort4*)(xq + (size_t)n * XROW + 4 * s) = o;
    }
}

// ---------- pack wtB[160][480] bf16 directly from W1..W5, Ws, Wv ----------
__global__ __launch_bounds__(256) void pack_kernel(
    const float* __restrict__ W1, const float* __restrict__ W2,
    const float* __restrict__ W3, const float* __restrict__ W4,
    const float* __restrict__ W5, const float* __restrict__ Ws,
    const float* __restrict__ Wv, unsigned short* __restrict__ wtB)
{
    const int o = blockIdx.x * 256 + threadIdx.x;
    if (o >= 160 * 480) return;
    const int f = o / 480, k = o % 480;
    float v = 0.f;
    if (f < 64) {
        if (k < 64) {
            float a = 0.f;
            for (int m = 0; m < 64; ++m) a += W1[k * 64 + m] * Ws[m * 64 + f];
            v = kLS * kC0 * a;
        } else if (k >= 256 && k < 288) {
            float a = 0.f;
            for (int m = 0; m < 64; ++m) a += W2[(k - 256) * 64 + m] * Ws[m * 64 + f];
            v = kLS * kC0 * a;
        }
    } else {
        const int w = (f - 64) / 3, i = (f - 64) % 3;
        if (k >= 64 + 64 * i && k < 128 + 64 * i) {
            float a = 0.f;
            const int kk = k - 64 - 64 * i;
            for (int m = 0; m < 32; ++m) a += W3[kk * 32 + m] * Wv[m * 32 + w];
            v = kLV * kC1 * a;
        } else if (k >= 288 + 32 * i && k < 320 + 32 * i) {
            float a = 0.f;
            const int kk = k - 288 - 32 * i;
            for (int m = 0; m < 32; ++m) a += W4[kk * 32 + m] * Wv[m * 32 + w];
            v = kLV * kC1 * a;
        } else if (k >= 384 + 32 * i && k < 416 + 32 * i) {
            float a = 0.f;
            const int kk = k - 384 - 32 * i;
            for (int m = 0; m < 32; ++m) a += W5[kk * 32 + m] * Wv[m * 32 + w];
            v = kLV * kC1 * a;
        }
    }
    wtB[o] = (unsigned short)f2bf(v);
}

// ---------- aggregation (bf16 gather, padded rows): 8-edge unroll ----------
__global__ __launch_bounds__(256, 8) void agg_bf16_kernel(
    const unsigned short* __restrict__ xq, const float4* __restrict__ shs,
    const int* __restrict__ srcs, const int* __restrict__ rowptr,
    unsigned short* __restrict__ st_all, int N)
{
    const int tid  = threadIdx.x;
    const int lane = tid & 63;
    const int wid  = tid >> 6;
    const bool lo  = (lane < 32);
    const int  w   = lane & 31;

    for (int n = blockIdx.x * 4 + wid; n < N; n += gridDim.x * 4) {
        const int beg = rowptr[n];
        const int end = rowptr[n + 1];

        float r0 = 0.f, r1 = 0.f, r2 = 0.f, r3 = 0.f;
        float a2 = 0.f, a4x = 0.f, a4y = 0.f, a4z = 0.f;
        float a5x = 0.f, a5y = 0.f, a5z = 0.f;

#define PAIR(SA, SB, SHA, SHB) do { \
            const unsigned short* xa = xq + (size_t)(SA) * XROW; \
            const unsigned short* xb = xq + (size_t)(SB) * XROW; \
            const float xsA = bf2f(xa[lane]); \
            const float xsB = bf2f(xb[lane]); \
            const unsigned short* xh = lo ? xa : xb; \
            const ushort4 v4 = *(const ushort4*)(xh + 64 + 4 * w); \
            const float va = bf2f(v4.x); \
            const float vb = bf2f(v4.y); \
            const float vc = bf2f(v4.z); \
            r0 += (SHA).x * xsA;  r0 += (SHB).x * xsB; \
            r1 += (SHA).y * xsA;  r1 += (SHB).y * xsB; \
            r2 += (SHA).z * xsA;  r2 += (SHB).z * xsB; \
            r3 += (SHA).w * xsA;  r3 += (SHB).w * xsB; \
            const float he0  = lo ? (SHA).x : (SHB).x; \
            const float he1x = lo ? (SHA).y : (SHB).y; \
            const float he1y = lo ? (SHA).z : (SHB).z; \
            const float he1z = lo ? (SHA).w : (SHB).w; \
            a2  += va * he1x + vb * he1y + vc * he1z; \
            a4x += he0 * va;  a4y += he0 * vb;  a4z += he0 * vc; \
            a5x += vb * he1z;  a5x -= vc * he1y; \
            a5y += vc * he1x;  a5y -= va * he1z; \
            a5z += va * he1y;  a5z -= vb * he1x; \
        } while (0)

        int idx = beg;
        for (; idx + 8 <= end; idx += 8) {
            const int4 sA4 = *(const int4*)(srcs + idx);
            const int4 sB4 = *(const int4*)(srcs + idx + 4);
            const float4 sh0 = shs[idx + 0];
            const float4 sh1 = shs[idx + 1];
            const float4 sh2 = shs[idx + 2];
            const float4 sh3 = shs[idx + 3];
            const float4 sh4 = shs[idx + 4];
            const float4 sh5 = shs[idx + 5];
            const float4 sh6 = shs[idx + 6];
            const float4 sh7 = shs[idx + 7];
            PAIR(sA4.x, sA4.y, sh0, sh1);
            PAIR(sA4.z, sA4.w, sh2, sh3);
            PAIR(sB4.x, sB4.y, sh4, sh5);
            PAIR(sB4.z, sB4.w, sh6, sh7);
        }
        for (; idx + 4 <= end; idx += 4) {
            const int4 s4 = *(const int4*)(srcs + idx);
            const float4 sh0 = shs[idx + 0];
            const float4 sh1 = shs[idx + 1];
            const float4 sh2 = shs[idx + 2];
            const float4 sh3 = shs[idx + 3];
            PAIR(s4.x, s4.y, sh0, sh1);
            PAIR(s4.z, s4.w, sh2, sh3);
        }
#undef PAIR

        a2  += __shfl_xor(a2, 32);
        a4x += __shfl_xor(a4x, 32);
        a4y += __shfl_xor(a4y, 32);
        a4z += __shfl_xor(a4z, 32);
        a5x += __shfl_xor(a5x, 32);
        a5y += __shfl_xor(a5y, 32);
        a5z += __shfl_xor(a5z, 32);

        unsigned short* sr = st_all + (size_t)n * 480;
        sr[lane]       = (unsigned short)f2bf(r0);
        sr[64 + lane]  = (unsigned short)f2bf(kINV3 * r1);
        sr[128 + lane] = (unsigned short)f2bf(kINV3 * r2);
        sr[192 + lane] = (unsigned short)f2bf(kINV3 * r3);
        sr[256 + lane] = (unsigned short)f2bf(kINV3 * (lo ? a2 : a4x));
        sr[320 + lane] = (unsigned short)f2bf(lo ? (kINV3 * a4y) : (kINV3 * a4z));
        sr[384 + lane] = (unsigned short)f2bf(lo ? (kINV6 * a5x) : (kINV6 * a5y));
        if (lo) sr[448 + lane] = (unsigned short)f2bf(kINV6 * a5z);
    }
}

// ---------- aggregation (fp32 fallback, round-13 verbatim) ----------
__global__ __launch_bounds__(256, 8) void agg_f32_kernel(
    const float* __restrict__ x, const float4* __restrict__ shs,
    const int* __restrict__ srcs, const int* __restrict__ rowptr,
    unsigned short* __restrict__ st_all, int N)
{
    const int tid  = threadIdx.x;
    const int lane = tid & 63;
    const int wid  = tid >> 6;
    const bool lo  = (lane < 32);
    const int  w   = lane & 31;

    for (int n = blockIdx.x * 4 + wid; n < N; n += gridDim.x * 4) {
        const int beg = rowptr[n];
        const int end = rowptr[n + 1];

        float r0 = 0.f, r1 = 0.f, r2 = 0.f, r3 = 0.f;
        float a2 = 0.f, a4x = 0.f, a4y = 0.f, a4z = 0.f;
        float a5x = 0.f, a5y = 0.f, a5z = 0.f;

#define PAIR(SA, SB, SHA, SHB) do { \
            const float* xa = x + (size_t)(SA) * DFEAT; \
            const float* xb = x + (size_t)(SB) * DFEAT; \
            const float xsA = xa[lane]; \
            const float xsB = xb[lane]; \
            const float* xh = lo ? xa : xb; \
            const float va = xh[64 + 3 * w]; \
            const float vb = xh[65 + 3 * w]; \
            const float vc = xh[66 + 3 * w]; \
            r0 += (SHA).x * xsA;  r0 += (SHB).x * xsB; \
            r1 += (SHA).y * xsA;  r1 += (SHB).y * xsB; \
            r2 += (SHA).z * xsA;  r2 += (SHB).z * xsB; \
            r3 += (SHA).w * xsA;  r3 += (SHB).w * xsB; \
            const float he0  = lo ? (SHA).x : (SHB).x; \
            const float he1x = lo ? (SHA).y : (SHB).y; \
            const float he1y = lo ? (SHA).z : (SHB).z; \
            const float he1z = lo ? (SHA).w : (SHB).w; \
            a2  += va * he1x + vb * he1y + vc * he1z; \
            a4x += he0 * va;  a4y += he0 * vb;  a4z += he0 * vc; \
            a5x += vb * he1z;  a5x -= vc * he1y; \
            a5y += vc * he1x;  a5y -= va * he1z; \
            a5z += va * he1y;  a5z -= vb * he1x; \
        } while (0)

        for (int idx = beg; idx < end; idx += 4) {
            const int4 s4 = *(const int4*)(srcs + idx);
            const float4 shA = shs[idx + 0];
            const float4 shB = shs[idx + 1];
            const float4 shC = shs[idx + 2];
            const float4 shD = shs[idx + 3];
            PAIR(s4.x, s4.y, shA, shB);
            PAIR(s4.z, s4.w, shC, shD);
        }
#undef PAIR

        a2  += __shfl_xor(a2, 32);
        a4x += __shfl_xor(a4x, 32);
        a4y += __shfl_xor(a4y, 32);
        a4z += __shfl_xor(a4z, 32);
        a5x += __shfl_xor(a5x, 32);
        a5y += __shfl_xor(a5y, 32);
        a5z += __shfl_xor(a5z, 32);

        unsigned short* sr = st_all + (size_t)n * 480;
        sr[lane]       = (unsigned short)f2bf(r0);
        sr[64 + lane]  = (unsigned short)f2bf(kINV3 * r1);
        sr[128 + lane] = (unsigned short)f2bf(kINV3 * r2);
        sr[192 + lane] = (unsigned short)f2bf(kINV3 * r3);
        sr[256 + lane] = (unsigned short)f2bf(kINV3 * (lo ? a2 : a4x));
        sr[320 + lane] = (unsigned short)f2bf(lo ? (kINV3 * a4y) : (kINV3 * a4z));
        sr[384 + lane] = (unsigned short)f2bf(lo ? (kINV6 * a5x) : (kINV6 * a5y));
        if (lo) sr[448 + lane] = (unsigned short)f2bf(kINV6 * a5z);
    }
}

// ---------- transform: MFMA, 16 nodes x 160 feats per wave ----------
__global__ __launch_bounds__(256, 4) void transform_kernel(
    const float* __restrict__ x, const unsigned short* __restrict__ st_all,
    const unsigned short* __restrict__ wtB, float* __restrict__ out, int N)
{
    __shared__ float sEp[4][16][17];
    const int tid  = threadIdx.x;
    const int lane = tid & 63;
    const int wid  = tid >> 6;
    const int l15  = lane & 15;
    const int pp   = lane >> 4;
    const int ntiles = (N + 15) >> 4;

    for (int tile = blockIdx.x * 4 + wid; tile < ntiles; tile += gridDim.x * 4) {
        const int n0 = tile * 16;
        const int nd = n0 + l15;
        const int ndc = (nd < N) ? nd : (N - 1);

        s8v a[15];
        #pragma unroll
        for (int kc = 0; kc < 15; ++kc)
            a[kc] = *(const s8v*)(st_all + (size_t)ndc * 480 + kc * 32 + pp * 8);

        for (int t = 0; t < 10; ++t) {
            f4v acc = (f4v){0.f, 0.f, 0.f, 0.f};
            const unsigned short* wrow = wtB + (size_t)(16 * t + l15) * 480 + pp * 8;
            if (t < 4) {  // hs rows: A1 (kc 0,1) + A2 (kc 8)
                acc = MFMA(a[0], *(const s8v*)(wrow + 0 * 32), acc);
                acc = MFMA(a[1], *(const s8v*)(wrow + 1 * 32), acc);
                acc = MFMA(a[8], *(const s8v*)(wrow + 8 * 32), acc);
            } else {      // hv rows: A3 (kc 2..7) + A4 (9..11) + A5 (12..14)
                #pragma unroll
                for (int kc = 2; kc <= 7; ++kc)
                    acc = MFMA(a[kc], *(const s8v*)(wrow + kc * 32), acc);
                #pragma unroll
                for (int kc = 9; kc <= 14; ++kc)
                    acc = MFMA(a[kc], *(const s8v*)(wrow + kc * 32), acc);
            }
            WAVE_SYNC();
            #pragma unroll
            for (int j = 0; j < 4; ++j)
                sEp[wid][pp * 4 + j][l15] = acc[j];
            WAVE_SYNC();
            #pragma unroll
            for (int it = 0; it < 4; ++it) {
                const int q  = it * 4 + pp;
                const int nq = n0 + q;
                if (nq < N) {
                    const float h = sEp[wid][q][l15];
                    const size_t off = (size_t)nq * DFEAT + 16 * t + l15;
                    out[off] = x[off] + fmaxf(h, 0.f);
                }
            }
        }
    }
}

extern "C" void kernel_launch(void* const* d_in, const int* in_sizes, int n_in,
                              void* d_out, int out_size, void* d_ws, size_t ws_size,
                              hipStream_t stream) {
    const float* x  = (const float*)d_in[0];
    const float* sh = (const float*)d_in[1];
    const float* W1 = (const float*)d_in[2];
    const float* W2 = (const float*)d_in[3];
    const float* W3 = (const float*)d_in[4];
    const float* W4 = (const float*)d_in[5];
    const float* W5 = (const float*)d_in[6];
    const float* Ws = (const float*)d_in[7];
    const float* Wv = (const float*)d_in[8];
    const int*   ei = (const int*)d_in[9];

    const int E = in_sizes[9] / 2;
    const int N = in_sizes[0] / DFEAT;
    const int* src = ei;
    const int* dst = ei + E;
    const int nb = (N + 1023) / 1024;
    const size_t Ep = (size_t)E + 3 * (size_t)N + 16;  // padded-edge capacity

    char* p = (char*)d_ws;
    float4* sh_sorted = (float4*)p;                 p += Ep * 16;
    unsigned short* st_all = (unsigned short*)p;    p += (size_t)N * 480 * 2;
    unsigned short* wtB = (unsigned short*)p;       p += 160 * 480 * 2;
    int* src_sorted = (int*)p;                      p += Ep * 4;
    int* deg = (int*)p;                             p += (size_t)N * 4;
    int* cursor = (int*)p;                          p += (size_t)N * 4;
    int* rowptr = (int*)p;                          p += ((size_t)N + 1) * 4;
    int* bsum = (int*)p;                            p += 1024;
    // optional padded-bf16 x copy, placed last; enabled only if workspace allows
    p = (char*)(((size_t)p + 15) & ~(size_t)15);
    unsigned short* xq = (unsigned short*)p;
    const size_t need_bf16 = (size_t)(p - (char*)d_ws) + (size_t)N * XROW * 2;
    const bool use_bf16 = (ws_size >= need_bf16);

    (void)hipMemsetAsync(deg, 0, (size_t)N * sizeof(int), stream);

    hist_kernel<<<512, 256, 0, stream>>>(dst, deg, E);
    blocksum_kernel<<<nb, 256, 0, stream>>>(deg, bsum, N);
    scanb_kernel<<<1, 64, 0, stream>>>(bsum, nb, rowptr + N);
    scanfinal_kernel<<<nb, 256, 0, stream>>>(deg, bsum, rowptr, cursor,
                                             src_sorted, sh_sorted, N);
    scatter_kernel<<<512, 256, 0, stream>>>(src, dst, (const float4*)sh, cursor,
                                            src_sorted, sh_sorted, E);
    pack_kernel<<<300, 256, 0, stream>>>(W1, W2, W3, W4, W5, Ws, Wv, wtB);
    if (use_bf16) {
        xcast_kernel<<<2048, 256, 0, stream>>>(x, xq, N);
        agg_bf16_kernel<<<2048, 256, 0, stream>>>(xq, (const float4*)sh_sorted,
                                                  src_sorted, rowptr, st_all, N);
    } else {
        agg_f32_kernel<<<2048, 256, 0, stream>>>(x, (const float4*)sh_sorted,
                                                 src_sorted, rowptr, st_all, N);
    }
    transform_kernel<<<800, 256, 0, stream>>>(x, st_all, wtB, (float*)d_out, N);
}

// Round 17
// 234.298 us; speedup vs baseline: 1.0928x; 1.0928x over previous
//
#include <hip/hip_runtime.h>

#define DFEAT 160

typedef float  f4v __attribute__((ext_vector_type(4)));
typedef short  s8v __attribute__((ext_vector_type(8)));

__device__ __constant__ float kINV3 = 0.57735026918962576451f;  // 1/sqrt(3)
__device__ __constant__ float kINV6 = 0.40824829046386301637f;  // 1/sqrt(6)
__device__ __constant__ float kC0   = 0.10206207261596575f;     // 1/sqrt(96)
__device__ __constant__ float kC1   = 0.15309310892394863f;     // sqrt(3/128)
__device__ __constant__ float kLS   = 0.125f;                   // 1/sqrt(64)
__device__ __constant__ float kLV   = 0.17677669529663687f;     // 1/sqrt(32)

#define WAVE_SYNC() do { \
    asm volatile("s_waitcnt lgkmcnt(0)" ::: "memory"); \
    __builtin_amdgcn_sched_barrier(0); \
} while (0)

#define MFMA(a, b, c) __builtin_amdgcn_mfma_f32_16x16x32_bf16((a), (b), (c), 0, 0, 0)

__device__ __forceinline__ unsigned f2bf(float f) {
    const unsigned u = __builtin_bit_cast(unsigned, f);
    const unsigned r = 0x7fffu + ((u >> 16) & 1u);
    return (u + r) >> 16;
}
__device__ __forceinline__ float bf2f(unsigned short u) {
    return __builtin_bit_cast(float, ((unsigned)u) << 16);
}

// ---------- CSR build (padded segments: deg rounded up to x4) ----------
__global__ void hist_kernel(const int* __restrict__ dst, int* __restrict__ deg, int E) {
    for (int e = blockIdx.x * blockDim.x + threadIdx.x; e < E; e += gridDim.x * blockDim.x)
        atomicAdd(&deg[dst[e]], 1);
}

__global__ __launch_bounds__(256) void blocksum_kernel(const int* __restrict__ deg,
                                                       int* __restrict__ bsum, int N) {
    __shared__ int red[256];
    const int b = blockIdx.x, t = threadIdx.x;
    const int base = b * 1024;
    int s = 0;
    for (int i = t; i < 1024; i += 256) {
        const int idx = base + i;
        if (idx < N) s += (deg[idx] + 3) & ~3;
    }
    red[t] = s;
    __syncthreads();
    for (int off = 128; off > 0; off >>= 1) {
        if (t < off) red[t] += red[t + off];
        __syncthreads();
    }
    if (t == 0) bsum[b] = red[0];
}

__global__ void scanb_kernel(int* __restrict__ bsum, int nb, int* __restrict__ rowptrN) {
    if (threadIdx.x == 0 && blockIdx.x == 0) {
        int run = 0;
        for (int i = 0; i < nb; ++i) { const int v = bsum[i]; bsum[i] = run; run += v; }
        *rowptrN = run;
    }
}

// also writes the <=3 filler slots per node (src=0, sh=0) so no big memsets needed
__global__ __launch_bounds__(256) void scanfinal_kernel(const int* __restrict__ deg,
                                                        const int* __restrict__ bsum,
                                                        int* __restrict__ rowptr,
                                                        int* __restrict__ cursor,
                                                        int* __restrict__ src_sorted,
                                                        float4* __restrict__ sh_sorted,
                                                        int N) {
    __shared__ int ts[256];
    const int b = blockIdx.x, t = threadIdx.x;
    const int i0 = b * 1024 + t * 4;
    int dO[4], dP[4];
    #pragma unroll
    for (int j = 0; j < 4; ++j) {
        dO[j] = (i0 + j < N) ? deg[i0 + j] : 0;
        dP[j] = (dO[j] + 3) & ~3;
    }
    ts[t] = dP[0] + dP[1] + dP[2] + dP[3];
    __syncthreads();
    for (int off = 1; off < 256; off <<= 1) {
        const int v = (t >= off) ? ts[t - off] : 0;
        __syncthreads();
        ts[t] += v;
        __syncthreads();
    }
    int ex = bsum[b] + ((t == 0) ? 0 : ts[t - 1]);
    const float4 z4 = make_float4(0.f, 0.f, 0.f, 0.f);
    #pragma unroll
    for (int j = 0; j < 4; ++j) {
        if (i0 + j < N) {
            rowptr[i0 + j] = ex;
            cursor[i0 + j] = ex;
            for (int f = ex + dO[j]; f < ex + dP[j]; ++f) {
                src_sorted[f] = 0;
                sh_sorted[f] = z4;
            }
            ex += dP[j];
        }
    }
}

// scatter into sorted streams (src + sh)
__global__ void scatter_kernel(const int* __restrict__ src, const int* __restrict__ dst,
                               const float4* __restrict__ sh, int* __restrict__ cursor,
                               int* __restrict__ src_sorted, float4* __restrict__ sh_sorted,
                               int E) {
    for (int e = blockIdx.x * blockDim.x + threadIdx.x; e < E; e += gridDim.x * blockDim.x) {
        const int pos = atomicAdd(&cursor[dst[e]], 1);
        src_sorted[pos] = src[e];
        sh_sorted[pos] = sh[e];
    }
}

// ---------- prep: x -> bf16 copy (dense 160-row) + pack wtB[160][480] ----------
// threads [0, 76800): wtB element o = i.  threads [76800, 76800+N*20): xq int4 slot.
__global__ __launch_bounds__(256) void prep_kernel(
    const float* __restrict__ x, int N,
    const float* __restrict__ W1, const float* __restrict__ W2,
    const float* __restrict__ W3, const float* __restrict__ W4,
    const float* __restrict__ W5, const float* __restrict__ Ws,
    const float* __restrict__ Wv,
    unsigned short* __restrict__ wtB, unsigned short* __restrict__ xq)
{
    const int total = 160 * 480 + N * 20;
    for (int i = blockIdx.x * 256 + threadIdx.x; i < total; i += gridDim.x * 256) {
        if (i < 160 * 480) {
            const int o = i;
            const int f = o / 480, k = o % 480;
            float v = 0.f;
            if (f < 64) {
                if (k < 64) {
                    float a = 0.f;
                    for (int m = 0; m < 64; ++m) a += W1[k * 64 + m] * Ws[m * 64 + f];
                    v = kLS * kC0 * a;
                } else if (k >= 256 && k < 288) {
                    float a = 0.f;
                    for (int m = 0; m < 64; ++m) a += W2[(k - 256) * 64 + m] * Ws[m * 64 + f];
                    v = kLS * kC0 * a;
                }
            } else {
                const int w = (f - 64) / 3, ii = (f - 64) % 3;
                if (k >= 64 + 64 * ii && k < 128 + 64 * ii) {
                    float a = 0.f;
                    const int kk = k - 64 - 64 * ii;
                    for (int m = 0; m < 32; ++m) a += W3[kk * 32 + m] * Wv[m * 32 + w];
                    v = kLV * kC1 * a;
                } else if (k >= 288 + 32 * ii && k < 320 + 32 * ii) {
                    float a = 0.f;
                    const int kk = k - 288 - 32 * ii;
                    for (int m = 0; m < 32; ++m) a += W4[kk * 32 + m] * Wv[m * 32 + w];
                    v = kLV * kC1 * a;
                } else if (k >= 384 + 32 * ii && k < 416 + 32 * ii) {
                    float a = 0.f;
                    const int kk = k - 384 - 32 * ii;
                    for (int m = 0; m < 32; ++m) a += W5[kk * 32 + m] * Wv[m * 32 + w];
                    v = kLV * kC1 * a;
                }
            }
            wtB[o] = (unsigned short)f2bf(v);
        } else {
            const int s = i - 160 * 480;   // int4 slot: 8 bf16 = 8 floats
            const float4 a = ((const float4*)x)[2 * s + 0];
            const float4 b = ((const float4*)x)[2 * s + 1];
            int4 o;
            o.x = (int)(f2bf(a.x) | (f2bf(a.y) << 16));
            o.y = (int)(f2bf(a.z) | (f2bf(a.w) << 16));
            o.z = (int)(f2bf(b.x) | (f2bf(b.y) << 16));
            o.w = (int)(f2bf(b.z) | (f2bf(b.w) << 16));
            ((int4*)xq)[s] = o;
        }
    }
}

// ---------- aggregation (bf16 gather, round-15 proven): wave/node; edge PAIRS ----------
__global__ __launch_bounds__(256, 8) void agg_bf16_kernel(
    const unsigned short* __restrict__ xq, const float4* __restrict__ shs,
    const int* __restrict__ srcs, const int* __restrict__ rowptr,
    unsigned short* __restrict__ st_all, int N)
{
    const int tid  = threadIdx.x;
    const int lane = tid & 63;
    const int wid  = tid >> 6;
    const bool lo  = (lane < 32);
    const int  w   = lane & 31;

    for (int n = blockIdx.x * 4 + wid; n < N; n += gridDim.x * 4) {
        const int beg = rowptr[n];
        const int end = rowptr[n + 1];

        float r0 = 0.f, r1 = 0.f, r2 = 0.f, r3 = 0.f;
        float a2 = 0.f, a4x = 0.f, a4y = 0.f, a4z = 0.f;
        float a5x = 0.f, a5y = 0.f, a5z = 0.f;

#define PAIR(SA, SB, SHA, SHB) do { \
            const unsigned short* xa = xq + (size_t)(SA) * DFEAT; \
            const unsigned short* xb = xq + (size_t)(SB) * DFEAT; \
            const float xsA = bf2f(xa[lane]); \
            const float xsB = bf2f(xb[lane]); \
            const unsigned short* xh = lo ? xa : xb; \
            const float va = bf2f(xh[64 + 3 * w]); \
            const float vb = bf2f(xh[65 + 3 * w]); \
            const float vc = bf2f(xh[66 + 3 * w]); \
            r0 += (SHA).x * xsA;  r0 += (SHB).x * xsB; \
            r1 += (SHA).y * xsA;  r1 += (SHB).y * xsB; \
            r2 += (SHA).z * xsA;  r2 += (SHB).z * xsB; \
            r3 += (SHA).w * xsA;  r3 += (SHB).w * xsB; \
            const float he0  = lo ? (SHA).x : (SHB).x; \
            const float he1x = lo ? (SHA).y : (SHB).y; \
            const float he1y = lo ? (SHA).z : (SHB).z; \
            const float he1z = lo ? (SHA).w : (SHB).w; \
            a2  += va * he1x + vb * he1y + vc * he1z; \
            a4x += he0 * va;  a4y += he0 * vb;  a4z += he0 * vc; \
            a5x += vb * he1z;  a5x -= vc * he1y; \
            a5y += vc * he1x;  a5y -= va * he1z; \
            a5z += va * he1y;  a5z -= vb * he1x; \
        } while (0)

        for (int idx = beg; idx < end; idx += 4) {
            const int4 s4 = *(const int4*)(srcs + idx);
            const float4 shA = shs[idx + 0];
            const float4 shB = shs[idx + 1];
            const float4 shC = shs[idx + 2];
            const float4 shD = shs[idx + 3];
            PAIR(s4.x, s4.y, shA, shB);
            PAIR(s4.z, s4.w, shC, shD);
        }
#undef PAIR

        a2  += __shfl_xor(a2, 32);
        a4x += __shfl_xor(a4x, 32);
        a4y += __shfl_xor(a4y, 32);
        a4z += __shfl_xor(a4z, 32);
        a5x += __shfl_xor(a5x, 32);
        a5y += __shfl_xor(a5y, 32);
        a5z += __shfl_xor(a5z, 32);

        unsigned short* sr = st_all + (size_t)n * 480;
        sr[lane]       = (unsigned short)f2bf(r0);
        sr[64 + lane]  = (unsigned short)f2bf(kINV3 * r1);
        sr[128 + lane] = (unsigned short)f2bf(kINV3 * r2);
        sr[192 + lane] = (unsigned short)f2bf(kINV3 * r3);
        sr[256 + lane] = (unsigned short)f2bf(kINV3 * (lo ? a2 : a4x));
        sr[320 + lane] = (unsigned short)f2bf(lo ? (kINV3 * a4y) : (kINV3 * a4z));
        sr[384 + lane] = (unsigned short)f2bf(lo ? (kINV6 * a5x) : (kINV6 * a5y));
        if (lo) sr[448 + lane] = (unsigned short)f2bf(kINV6 * a5z);
    }
}

// ---------- aggregation (fp32 fallback, round-13 verbatim) ----------
__global__ __launch_bounds__(256, 8) void agg_f32_kernel(
    const float* __restrict__ x, const float4* __restrict__ shs,
    const int* __restrict__ srcs, const int* __restrict__ rowptr,
    unsigned short* __restrict__ st_all, int N)
{
    const int tid  = threadIdx.x;
    const int lane = tid & 63;
    const int wid  = tid >> 6;
    const bool lo  = (lane < 32);
    const int  w   = lane & 31;

    for (int n = blockIdx.x * 4 + wid; n < N; n += gridDim.x * 4) {
        const int beg = rowptr[n];
        const int end = rowptr[n + 1];

        float r0 = 0.f, r1 = 0.f, r2 = 0.f, r3 = 0.f;
        float a2 = 0.f, a4x = 0.f, a4y = 0.f, a4z = 0.f;
        float a5x = 0.f, a5y = 0.f, a5z = 0.f;

#define PAIR(SA, SB, SHA, SHB) do { \
            const float* xa = x + (size_t)(SA) * DFEAT; \
            const float* xb = x + (size_t)(SB) * DFEAT; \
            const float xsA = xa[lane]; \
            const float xsB = xb[lane]; \
            const float* xh = lo ? xa : xb; \
            const float va = xh[64 + 3 * w]; \
            const float vb = xh[65 + 3 * w]; \
            const float vc = xh[66 + 3 * w]; \
            r0 += (SHA).x * xsA;  r0 += (SHB).x * xsB; \
            r1 += (SHA).y * xsA;  r1 += (SHB).y * xsB; \
            r2 += (SHA).z * xsA;  r2 += (SHB).z * xsB; \
            r3 += (SHA).w * xsA;  r3 += (SHB).w * xsB; \
            const float he0  = lo ? (SHA).x : (SHB).x; \
            const float he1x = lo ? (SHA).y : (SHB).y; \
            const float he1y = lo ? (SHA).z : (SHB).z; \
            const float he1z = lo ? (SHA).w : (SHB).w; \
            a2  += va * he1x + vb * he1y + vc * he1z; \
            a4x += he0 * va;  a4y += he0 * vb;  a4z += he0 * vc; \
            a5x += vb * he1z;  a5x -= vc * he1y; \
            a5y += vc * he1x;  a5y -= va * he1z; \
            a5z += va * he1y;  a5z -= vb * he1x; \
        } while (0)

        for (int idx = beg; idx < end; idx += 4) {
            const int4 s4 = *(const int4*)(srcs + idx);
            const float4 shA = shs[idx + 0];
            const float4 shB = shs[idx + 1];
            const float4 shC = shs[idx + 2];
            const float4 shD = shs[idx + 3];
            PAIR(s4.x, s4.y, shA, shB);
            PAIR(s4.z, s4.w, shC, shD);
        }
#undef PAIR

        a2  += __shfl_xor(a2, 32);
        a4x += __shfl_xor(a4x, 32);
        a4y += __shfl_xor(a4y, 32);
        a4z += __shfl_xor(a4z, 32);
        a5x += __shfl_xor(a5x, 32);
        a5y += __shfl_xor(a5y, 32);
        a5z += __shfl_xor(a5z, 32);

        unsigned short* sr = st_all + (size_t)n * 480;
        sr[lane]       = (unsigned short)f2bf(r0);
        sr[64 + lane]  = (unsigned short)f2bf(kINV3 * r1);
        sr[128 + lane] = (unsigned short)f2bf(kINV3 * r2);
        sr[192 + lane] = (unsigned short)f2bf(kINV3 * r3);
        sr[256 + lane] = (unsigned short)f2bf(kINV3 * (lo ? a2 : a4x));
        sr[320 + lane] = (unsigned short)f2bf(lo ? (kINV3 * a4y) : (kINV3 * a4z));
        sr[384 + lane] = (unsigned short)f2bf(lo ? (kINV6 * a5x) : (kINV6 * a5y));
        if (lo) sr[448 + lane] = (unsigned short)f2bf(kINV6 * a5z);
    }
}

// ---------- transform: MFMA, 16 nodes x 160 feats per wave ----------
__global__ __launch_bounds__(256, 4) void transform_kernel(
    const float* __restrict__ x, const unsigned short* __restrict__ st_all,
    const unsigned short* __restrict__ wtB, float* __restrict__ out, int N)
{
    __shared__ float sEp[4][16][17];
    const int tid  = threadIdx.x;
    const int lane = tid & 63;
    const int wid  = tid >> 6;
    const int l15  = lane & 15;
    const int pp   = lane >> 4;
    const int ntiles = (N + 15) >> 4;

    for (int tile = blockIdx.x * 4 + wid; tile < ntiles; tile += gridDim.x * 4) {
        const int n0 = tile * 16;
        const int nd = n0 + l15;
        const int ndc = (nd < N) ? nd : (N - 1);

        s8v a[15];
        #pragma unroll
        for (int kc = 0; kc < 15; ++kc)
            a[kc] = *(const s8v*)(st_all + (size_t)ndc * 480 + kc * 32 + pp * 8);

        for (int t = 0; t < 10; ++t) {
            f4v acc = (f4v){0.f, 0.f, 0.f, 0.f};
            const unsigned short* wrow = wtB + (size_t)(16 * t + l15) * 480 + pp * 8;
            if (t < 4) {  // hs rows: A1 (kc 0,1) + A2 (kc 8)
                acc = MFMA(a[0], *(const s8v*)(wrow + 0 * 32), acc);
                acc = MFMA(a[1], *(const s8v*)(wrow + 1 * 32), acc);
                acc = MFMA(a[8], *(const s8v*)(wrow + 8 * 32), acc);
            } else {      // hv rows: A3 (kc 2..7) + A4 (9..11) + A5 (12..14)
                #pragma unroll
                for (int kc = 2; kc <= 7; ++kc)
                    acc = MFMA(a[kc], *(const s8v*)(wrow + kc * 32), acc);
                #pragma unroll
                for (int kc = 9; kc <= 14; ++kc)
                    acc = MFMA(a[kc], *(const s8v*)(wrow + kc * 32), acc);
            }
            WAVE_SYNC();
            #pragma unroll
            for (int j = 0; j < 4; ++j)
                sEp[wid][pp * 4 + j][l15] = acc[j];
            WAVE_SYNC();
            #pragma unroll
            for (int it = 0; it < 4; ++it) {
                const int q  = it * 4 + pp;
                const int nq = n0 + q;
                if (nq < N) {
                    const float h = sEp[wid][q][l15];
                    const size_t off = (size_t)nq * DFEAT + 16 * t + l15;
                    out[off] = x[off] + fmaxf(h, 0.f);
                }
            }
        }
    }
}

extern "C" void kernel_launch(void* const* d_in, const int* in_sizes, int n_in,
                              void* d_out, int out_size, void* d_ws, size_t ws_size,
                              hipStream_t stream) {
    const float* x  = (const float*)d_in[0];
    const float* sh = (const float*)d_in[1];
    const float* W1 = (const float*)d_in[2];
    const float* W2 = (const float*)d_in[3];
    const float* W3 = (const float*)d_in[4];
    const float* W4 = (const float*)d_in[5];
    const float* W5 = (const float*)d_in[6];
    const float* Ws = (const float*)d_in[7];
    const float* Wv = (const float*)d_in[8];
    const int*   ei = (const int*)d_in[9];

    const int E = in_sizes[9] / 2;
    const int N = in_sizes[0] / DFEAT;
    const int* src = ei;
    const int* dst = ei + E;
    const int nb = (N + 1023) / 1024;
    const size_t Ep = (size_t)E + 3 * (size_t)N + 16;  // padded-edge capacity

    char* p = (char*)d_ws;
    float4* sh_sorted = (float4*)p;                 p += Ep * 16;
    unsigned short* st_all = (unsigned short*)p;    p += (size_t)N * 480 * 2;
    unsigned short* wtB = (unsigned short*)p;       p += 160 * 480 * 2;
    int* src_sorted = (int*)p;                      p += Ep * 4;
    int* deg = (int*)p;                             p += (size_t)N * 4;
    int* cursor = (int*)p;                          p += (size_t)N * 4;
    int* rowptr = (int*)p;                          p += ((size_t)N + 1) * 4;
    int* bsum = (int*)p;                            p += 1024;
    // optional bf16 x copy, placed last; enabled only if workspace allows
    p = (char*)(((size_t)p + 15) & ~(size_t)15);
    unsigned short* xq = (unsigned short*)p;
    const size_t need_bf16 = (size_t)(p - (char*)d_ws) + (size_t)N * DFEAT * 2;
    const bool use_bf16 = (ws_size >= need_bf16);

    (void)hipMemsetAsync(deg, 0, (size_t)N * sizeof(int), stream);

    hist_kernel<<<1024, 256, 0, stream>>>(dst, deg, E);
    blocksum_kernel<<<nb, 256, 0, stream>>>(deg, bsum, N);
    scanb_kernel<<<1, 64, 0, stream>>>(bsum, nb, rowptr + N);
    scanfinal_kernel<<<nb, 256, 0, stream>>>(deg, bsum, rowptr, cursor,
                                             src_sorted, sh_sorted, N);
    scatter_kernel<<<1024, 256, 0, stream>>>(src, dst, (const float4*)sh, cursor,
                                             src_sorted, sh_sorted, E);
    if (use_bf16) {
        prep_kernel<<<2048, 256, 0, stream>>>(x, N, W1, W2, W3, W4, W5, Ws, Wv, wtB, xq);
        agg_bf16_kernel<<<2048, 256, 0, stream>>>(xq, (const float4*)sh_sorted,
                                                  src_sorted, rowptr, st_all, N);
    } else {
        prep_kernel<<<2048, 256, 0, stream>>>(x, 0, W1, W2, W3, W4, W5, Ws, Wv, wtB, xq);
        agg_f32_kernel<<<2048, 256, 0, stream>>>(x, (const float4*)sh_sorted,
                                                 src_sorted, rowptr, st_all, N);
    }
    transform_kernel<<<800, 256, 0, stream>>>(x, st_all, wtB, (float*)d_out, N);
}

// Round 18
// 233.565 us; speedup vs baseline: 1.0963x; 1.0031x over previous
//
#include <hip/hip_runtime.h>

#define DFEAT 160
#define STRIDE 488   // u16 LDS row stride (480 + pad)

typedef float  f4v __attribute__((ext_vector_type(4)));
typedef short  s8v __attribute__((ext_vector_type(8)));

__device__ __constant__ float kINV3 = 0.57735026918962576451f;  // 1/sqrt(3)
__device__ __constant__ float kINV6 = 0.40824829046386301637f;  // 1/sqrt(6)
__device__ __constant__ float kC0   = 0.10206207261596575f;     // 1/sqrt(96)
__device__ __constant__ float kC1   = 0.15309310892394863f;     // sqrt(3/128)
__device__ __constant__ float kLS   = 0.125f;                   // 1/sqrt(64)
__device__ __constant__ float kLV   = 0.17677669529663687f;     // 1/sqrt(32)

#define WAVE_SYNC() do { \
    asm volatile("s_waitcnt lgkmcnt(0)" ::: "memory"); \
    __builtin_amdgcn_sched_barrier(0); \
} while (0)

#define MFMA(a, b, c) __builtin_amdgcn_mfma_f32_16x16x32_bf16((a), (b), (c), 0, 0, 0)

__device__ __forceinline__ unsigned f2bf(float f) {
    const unsigned u = __builtin_bit_cast(unsigned, f);
    const unsigned r = 0x7fffu + ((u >> 16) & 1u);
    return (u + r) >> 16;
}
__device__ __forceinline__ float bf2f(unsigned short u) {
    return __builtin_bit_cast(float, ((unsigned)u) << 16);
}

// ---------- CSR build (padded segments: deg rounded up to x4) ----------
__global__ void hist_kernel(const int* __restrict__ dst, int* __restrict__ deg, int E) {
    for (int e = blockIdx.x * blockDim.x + threadIdx.x; e < E; e += gridDim.x * blockDim.x)
        atomicAdd(&deg[dst[e]], 1);
}

__global__ __launch_bounds__(256) void blocksum_kernel(const int* __restrict__ deg,
                                                       int* __restrict__ bsum, int N) {
    __shared__ int red[256];
    const int b = blockIdx.x, t = threadIdx.x;
    const int base = b * 1024;
    int s = 0;
    for (int i = t; i < 1024; i += 256) {
        const int idx = base + i;
        if (idx < N) s += (deg[idx] + 3) & ~3;
    }
    red[t] = s;
    __syncthreads();
    for (int off = 128; off > 0; off >>= 1) {
        if (t < off) red[t] += red[t + off];
        __syncthreads();
    }
    if (t == 0) bsum[b] = red[0];
}

__global__ void scanb_kernel(int* __restrict__ bsum, int nb, int* __restrict__ rowptrN) {
    if (threadIdx.x == 0 && blockIdx.x == 0) {
        int run = 0;
        for (int i = 0; i < nb; ++i) { const int v = bsum[i]; bsum[i] = run; run += v; }
        *rowptrN = run;
    }
}

// also writes the <=3 filler slots per node (src=0, sh=0) so no big memsets needed
__global__ __launch_bounds__(256) void scanfinal_kernel(const int* __restrict__ deg,
                                                        const int* __restrict__ bsum,
                                                        int* __restrict__ rowptr,
                                                        int* __restrict__ cursor,
                                                        int* __restrict__ src_sorted,
                                                        float4* __restrict__ sh_sorted,
                                                        int N) {
    __shared__ int ts[256];
    const int b = blockIdx.x, t = threadIdx.x;
    const int i0 = b * 1024 + t * 4;
    int dO[4], dP[4];
    #pragma unroll
    for (int j = 0; j < 4; ++j) {
        dO[j] = (i0 + j < N) ? deg[i0 + j] : 0;
        dP[j] = (dO[j] + 3) & ~3;
    }
    ts[t] = dP[0] + dP[1] + dP[2] + dP[3];
    __syncthreads();
    for (int off = 1; off < 256; off <<= 1) {
        const int v = (t >= off) ? ts[t - off] : 0;
        __syncthreads();
        ts[t] += v;
        __syncthreads();
    }
    int ex = bsum[b] + ((t == 0) ? 0 : ts[t - 1]);
    const float4 z4 = make_float4(0.f, 0.f, 0.f, 0.f);
    #pragma unroll
    for (int j = 0; j < 4; ++j) {
        if (i0 + j < N) {
            rowptr[i0 + j] = ex;
            cursor[i0 + j] = ex;
            for (int f = ex + dO[j]; f < ex + dP[j]; ++f) {
                src_sorted[f] = 0;
                sh_sorted[f] = z4;
            }
            ex += dP[j];
        }
    }
}

// scatter into sorted streams (src + sh)
__global__ void scatter_kernel(const int* __restrict__ src, const int* __restrict__ dst,
                               const float4* __restrict__ sh, int* __restrict__ cursor,
                               int* __restrict__ src_sorted, float4* __restrict__ sh_sorted,
                               int E) {
    for (int e = blockIdx.x * blockDim.x + threadIdx.x; e < E; e += gridDim.x * blockDim.x) {
        const int pos = atomicAdd(&cursor[dst[e]], 1);
        src_sorted[pos] = src[e];
        sh_sorted[pos] = sh[e];
    }
}

// ---------- prep: x -> bf16 copy (dense 160-row) + pack wtB[160][480] ----------
__global__ __launch_bounds__(256) void prep_kernel(
    const float* __restrict__ x, int N,
    const float* __restrict__ W1, const float* __restrict__ W2,
    const float* __restrict__ W3, const float* __restrict__ W4,
    const float* __restrict__ W5, const float* __restrict__ Ws,
    const float* __restrict__ Wv,
    unsigned short* __restrict__ wtB, unsigned short* __restrict__ xq)
{
    const int total = 160 * 480 + N * 20;
    for (int i = blockIdx.x * 256 + threadIdx.x; i < total; i += gridDim.x * 256) {
        if (i < 160 * 480) {
            const int o = i;
            const int f = o / 480, k = o % 480;
            float v = 0.f;
            if (f < 64) {
                if (k < 64) {
                    float a = 0.f;
                    for (int m = 0; m < 64; ++m) a += W1[k * 64 + m] * Ws[m * 64 + f];
                    v = kLS * kC0 * a;
                } else if (k >= 256 && k < 288) {
                    float a = 0.f;
                    for (int m = 0; m < 64; ++m) a += W2[(k - 256) * 64 + m] * Ws[m * 64 + f];
                    v = kLS * kC0 * a;
                }
            } else {
                const int w = (f - 64) / 3, ii = (f - 64) % 3;
                if (k >= 64 + 64 * ii && k < 128 + 64 * ii) {
                    float a = 0.f;
                    const int kk = k - 64 - 64 * ii;
                    for (int m = 0; m < 32; ++m) a += W3[kk * 32 + m] * Wv[m * 32 + w];
                    v = kLV * kC1 * a;
                } else if (k >= 288 + 32 * ii && k < 320 + 32 * ii) {
                    float a = 0.f;
                    const int kk = k - 288 - 32 * ii;
                    for (int m = 0; m < 32; ++m) a += W4[kk * 32 + m] * Wv[m * 32 + w];
                    v = kLV * kC1 * a;
                } else if (k >= 384 + 32 * ii && k < 416 + 32 * ii) {
                    float a = 0.f;
                    const int kk = k - 384 - 32 * ii;
                    for (int m = 0; m < 32; ++m) a += W5[kk * 32 + m] * Wv[m * 32 + w];
                    v = kLV * kC1 * a;
                }
            }
            wtB[o] = (unsigned short)f2bf(v);
        } else {
            const int s = i - 160 * 480;   // int4 slot: 8 bf16 = 8 floats
            const float4 a = ((const float4*)x)[2 * s + 0];
            const float4 b = ((const float4*)x)[2 * s + 1];
            int4 o;
            o.x = (int)(f2bf(a.x) | (f2bf(a.y) << 16));
            o.y = (int)(f2bf(a.z) | (f2bf(a.w) << 16));
            o.z = (int)(f2bf(b.x) | (f2bf(b.y) << 16));
            o.w = (int)(f2bf(b.z) | (f2bf(b.w) << 16));
            ((int4*)xq)[s] = o;
        }
    }
}

// ---------- fused agg (LDS state) + MFMA transform: ONE 16-node tile per block ----------
__global__ __launch_bounds__(256, 8) void fused_kernel(
    const unsigned short* __restrict__ xq, const float* __restrict__ x,
    const float4* __restrict__ shs, const int* __restrict__ srcs,
    const int* __restrict__ rowptr, const unsigned short* __restrict__ wtB,
    float* __restrict__ out, int N)
{
    __shared__ unsigned short st[16 * STRIDE];

    const int tid  = threadIdx.x;
    const int lane = tid & 63;
    const int wid  = tid >> 6;
    const bool lo  = (lane < 32);
    const int  w   = lane & 31;
    const int  l15 = lane & 15;
    const int  pp  = lane >> 4;
    const int ntiles = (N + 15) >> 4;

    for (int tile = blockIdx.x; tile < ntiles; tile += gridDim.x) {
        const int n0 = tile << 4;

        // ===== phase 1: wave wid aggregates nodes n0+4*wid .. +3 -> st rows =====
        for (int j = 0; j < 4; ++j) {
            const int q = 4 * wid + j;
            const int n = n0 + q;
            if (n < N) {
                const int beg = rowptr[n];
                const int end = rowptr[n + 1];

                float r0 = 0.f, r1 = 0.f, r2 = 0.f, r3 = 0.f;
                float a2 = 0.f, a4x = 0.f, a4y = 0.f, a4z = 0.f;
                float a5x = 0.f, a5y = 0.f, a5z = 0.f;

#define PAIR(SA, SB, SHA, SHB) do { \
                const unsigned short* xa = xq + (size_t)(SA) * DFEAT; \
                const unsigned short* xb = xq + (size_t)(SB) * DFEAT; \
                const float xsA = bf2f(xa[lane]); \
                const float xsB = bf2f(xb[lane]); \
                const unsigned short* xh = lo ? xa : xb; \
                const float va = bf2f(xh[64 + 3 * w]); \
                const float vb = bf2f(xh[65 + 3 * w]); \
                const float vc = bf2f(xh[66 + 3 * w]); \
                r0 += (SHA).x * xsA;  r0 += (SHB).x * xsB; \
                r1 += (SHA).y * xsA;  r1 += (SHB).y * xsB; \
                r2 += (SHA).z * xsA;  r2 += (SHB).z * xsB; \
                r3 += (SHA).w * xsA;  r3 += (SHB).w * xsB; \
                const float he0  = lo ? (SHA).x : (SHB).x; \
                const float he1x = lo ? (SHA).y : (SHB).y; \
                const float he1y = lo ? (SHA).z : (SHB).z; \
                const float he1z = lo ? (SHA).w : (SHB).w; \
                a2  += va * he1x + vb * he1y + vc * he1z; \
                a4x += he0 * va;  a4y += he0 * vb;  a4z += he0 * vc; \
                a5x += vb * he1z;  a5x -= vc * he1y; \
                a5y += vc * he1x;  a5y -= va * he1z; \
                a5z += va * he1y;  a5z -= vb * he1x; \
            } while (0)

                for (int idx = beg; idx < end; idx += 4) {
                    const int4 s4 = *(const int4*)(srcs + idx);
                    const float4 shA = shs[idx + 0];
                    const float4 shB = shs[idx + 1];
                    const float4 shC = shs[idx + 2];
                    const float4 shD = shs[idx + 3];
                    PAIR(s4.x, s4.y, shA, shB);
                    PAIR(s4.z, s4.w, shC, shD);
                }
#undef PAIR

                a2  += __shfl_xor(a2, 32);
                a4x += __shfl_xor(a4x, 32);
                a4y += __shfl_xor(a4y, 32);
                a4z += __shfl_xor(a4z, 32);
                a5x += __shfl_xor(a5x, 32);
                a5y += __shfl_xor(a5y, 32);
                a5z += __shfl_xor(a5z, 32);

                unsigned short* sr = st + q * STRIDE;
                sr[lane]       = (unsigned short)f2bf(r0);
                sr[64 + lane]  = (unsigned short)f2bf(kINV3 * r1);
                sr[128 + lane] = (unsigned short)f2bf(kINV3 * r2);
                sr[192 + lane] = (unsigned short)f2bf(kINV3 * r3);
                sr[256 + lane] = (unsigned short)f2bf(kINV3 * (lo ? a2 : a4x));
                sr[320 + lane] = (unsigned short)f2bf(lo ? (kINV3 * a4y) : (kINV3 * a4z));
                sr[384 + lane] = (unsigned short)f2bf(lo ? (kINV6 * a5x) : (kINV6 * a5y));
                if (lo) sr[448 + lane] = (unsigned short)f2bf(kINV6 * a5z);
            }
        }
        __syncthreads();

        // ===== phase 2: 4 waves split the 10 feature-column tiles =====
        const unsigned short* arow = st + l15 * STRIDE + pp * 8;
        for (int t = wid; t < 10; t += 4) {
            f4v acc = (f4v){0.f, 0.f, 0.f, 0.f};
            const unsigned short* wrow = wtB + (size_t)(16 * t + l15) * 480 + pp * 8;
            if (t < 4) {  // hs rows: A1 (kc 0,1) + A2 (kc 8)
                acc = MFMA(*(const s8v*)(arow + 0 * 32), *(const s8v*)(wrow + 0 * 32), acc);
                acc = MFMA(*(const s8v*)(arow + 1 * 32), *(const s8v*)(wrow + 1 * 32), acc);
                acc = MFMA(*(const s8v*)(arow + 8 * 32), *(const s8v*)(wrow + 8 * 32), acc);
            } else {      // hv rows: A3 (kc 2..7) + A4 (9..11) + A5 (12..14)
                #pragma unroll
                for (int kc = 2; kc <= 7; ++kc)
                    acc = MFMA(*(const s8v*)(arow + kc * 32), *(const s8v*)(wrow + kc * 32), acc);
                #pragma unroll
                for (int kc = 9; kc <= 14; ++kc)
                    acc = MFMA(*(const s8v*)(arow + kc * 32), *(const s8v*)(wrow + kc * 32), acc);
            }
            // D (m89): row = node = pp*4+j, col = feat = 16t+l15
            #pragma unroll
            for (int j = 0; j < 4; ++j) {
                const int nq = n0 + pp * 4 + j;
                if (nq < N) {
                    const size_t off = (size_t)nq * DFEAT + 16 * t + l15;
                    out[off] = x[off] + fmaxf(acc[j], 0.f);
                }
            }
        }
        __syncthreads();  // st reads done before any next-tile writes
    }
}

// ---------- fp32 fallback path (round-17 verbatim) ----------
__global__ __launch_bounds__(256, 8) void agg_f32_kernel(
    const float* __restrict__ x, const float4* __restrict__ shs,
    const int* __restrict__ srcs, const int* __restrict__ rowptr,
    unsigned short* __restrict__ st_all, int N)
{
    const int tid  = threadIdx.x;
    const int lane = tid & 63;
    const int wid  = tid >> 6;
    const bool lo  = (lane < 32);
    const int  w   = lane & 31;

    for (int n = blockIdx.x * 4 + wid; n < N; n += gridDim.x * 4) {
        const int beg = rowptr[n];
        const int end = rowptr[n + 1];

        float r0 = 0.f, r1 = 0.f, r2 = 0.f, r3 = 0.f;
        float a2 = 0.f, a4x = 0.f, a4y = 0.f, a4z = 0.f;
        float a5x = 0.f, a5y = 0.f, a5z = 0.f;

#define PAIR(SA, SB, SHA, SHB) do { \
            const float* xa = x + (size_t)(SA) * DFEAT; \
            const float* xb = x + (size_t)(SB) * DFEAT; \
            const float xsA = xa[lane]; \
            const float xsB = xb[lane]; \
            const float* xh = lo ? xa : xb; \
            const float va = xh[64 + 3 * w]; \
            const float vb = xh[65 + 3 * w]; \
            const float vc = xh[66 + 3 * w]; \
            r0 += (SHA).x * xsA;  r0 += (SHB).x * xsB; \
            r1 += (SHA).y * xsA;  r1 += (SHB).y * xsB; \
            r2 += (SHA).z * xsA;  r2 += (SHB).z * xsB; \
            r3 += (SHA).w * xsA;  r3 += (SHB).w * xsB; \
            const float he0  = lo ? (SHA).x : (SHB).x; \
            const float he1x = lo ? (SHA).y : (SHB).y; \
            const float he1y = lo ? (SHA).z : (SHB).z; \
            const float he1z = lo ? (SHA).w : (SHB).w; \
            a2  += va * he1x + vb * he1y + vc * he1z; \
            a4x += he0 * va;  a4y += he0 * vb;  a4z += he0 * vc; \
            a5x += vb * he1z;  a5x -= vc * he1y; \
            a5y += vc * he1x;  a5y -= va * he1z; \
            a5z += va * he1y;  a5z -= vb * he1x; \
        } while (0)

        for (int idx = beg; idx < end; idx += 4) {
            const int4 s4 = *(const int4*)(srcs + idx);
            const float4 shA = shs[idx + 0];
            const float4 shB = shs[idx + 1];
            const float4 shC = shs[idx + 2];
            const float4 shD = shs[idx + 3];
            PAIR(s4.x, s4.y, shA, shB);
            PAIR(s4.z, s4.w, shC, shD);
        }
#undef PAIR

        a2  += __shfl_xor(a2, 32);
        a4x += __shfl_xor(a4x, 32);
        a4y += __shfl_xor(a4y, 32);
        a4z += __shfl_xor(a4z, 32);
        a5x += __shfl_xor(a5x, 32);
        a5y += __shfl_xor(a5y, 32);
        a5z += __shfl_xor(a5z, 32);

        unsigned short* sr = st_all + (size_t)n * 480;
        sr[lane]       = (unsigned short)f2bf(r0);
        sr[64 + lane]  = (unsigned short)f2bf(kINV3 * r1);
        sr[128 + lane] = (unsigned short)f2bf(kINV3 * r2);
        sr[192 + lane] = (unsigned short)f2bf(kINV3 * r3);
        sr[256 + lane] = (unsigned short)f2bf(kINV3 * (lo ? a2 : a4x));
        sr[320 + lane] = (unsigned short)f2bf(lo ? (kINV3 * a4y) : (kINV3 * a4z));
        sr[384 + lane] = (unsigned short)f2bf(lo ? (kINV6 * a5x) : (kINV6 * a5y));
        if (lo) sr[448 + lane] = (unsigned short)f2bf(kINV6 * a5z);
    }
}

__global__ __launch_bounds__(256, 4) void transform_kernel(
    const float* __restrict__ x, const unsigned short* __restrict__ st_all,
    const unsigned short* __restrict__ wtB, float* __restrict__ out, int N)
{
    __shared__ float sEp[4][16][17];
    const int tid  = threadIdx.x;
    const int lane = tid & 63;
    const int wid  = tid >> 6;
    const int l15  = lane & 15;
    const int pp   = lane >> 4;
    const int ntiles = (N + 15) >> 4;

    for (int tile = blockIdx.x * 4 + wid; tile < ntiles; tile += gridDim.x * 4) {
        const int n0 = tile * 16;
        const int nd = n0 + l15;
        const int ndc = (nd < N) ? nd : (N - 1);

        s8v a[15];
        #pragma unroll
        for (int kc = 0; kc < 15; ++kc)
            a[kc] = *(const s8v*)(st_all + (size_t)ndc * 480 + kc * 32 + pp * 8);

        for (int t = 0; t < 10; ++t) {
            f4v acc = (f4v){0.f, 0.f, 0.f, 0.f};
            const unsigned short* wrow = wtB + (size_t)(16 * t + l15) * 480 + pp * 8;
            if (t < 4) {
                acc = MFMA(a[0], *(const s8v*)(wrow + 0 * 32), acc);
                acc = MFMA(a[1], *(const s8v*)(wrow + 1 * 32), acc);
                acc = MFMA(a[8], *(const s8v*)(wrow + 8 * 32), acc);
            } else {
                #pragma unroll
                for (int kc = 2; kc <= 7; ++kc)
                    acc = MFMA(a[kc], *(const s8v*)(wrow + kc * 32), acc);
                #pragma unroll
                for (int kc = 9; kc <= 14; ++kc)
                    acc = MFMA(a[kc], *(const s8v*)(wrow + kc * 32), acc);
            }
            WAVE_SYNC();
            #pragma unroll
            for (int j = 0; j < 4; ++j)
                sEp[wid][pp * 4 + j][l15] = acc[j];
            WAVE_SYNC();
            #pragma unroll
            for (int it = 0; it < 4; ++it) {
                const int q  = it * 4 + pp;
                const int nq = n0 + q;
                if (nq < N) {
                    const float h = sEp[wid][q][l15];
                    const size_t off = (size_t)nq * DFEAT + 16 * t + l15;
                    out[off] = x[off] + fmaxf(h, 0.f);
                }
            }
        }
    }
}

extern "C" void kernel_launch(void* const* d_in, const int* in_sizes, int n_in,
                              void* d_out, int out_size, void* d_ws, size_t ws_size,
                              hipStream_t stream) {
    const float* x  = (const float*)d_in[0];
    const float* sh = (const float*)d_in[1];
    const float* W1 = (const float*)d_in[2];
    const float* W2 = (const float*)d_in[3];
    const float* W3 = (const float*)d_in[4];
    const float* W4 = (const float*)d_in[5];
    const float* W5 = (const float*)d_in[6];
    const float* Ws = (const float*)d_in[7];
    const float* Wv = (const float*)d_in[8];
    const int*   ei = (const int*)d_in[9];

    const int E = in_sizes[9] / 2;
    const int N = in_sizes[0] / DFEAT;
    const int* src = ei;
    const int* dst = ei + E;
    const int nb = (N + 1023) / 1024;
    const int ntiles = (N + 15) >> 4;
    const size_t Ep = (size_t)E + 3 * (size_t)N + 16;  // padded-edge capacity

    char* p = (char*)d_ws;
    float4* sh_sorted = (float4*)p;                 p += Ep * 16;
    unsigned short* st_all = (unsigned short*)p;    p += (size_t)N * 480 * 2;  // fallback only
    unsigned short* wtB = (unsigned short*)p;       p += 160 * 480 * 2;
    int* src_sorted = (int*)p;                      p += Ep * 4;
    int* deg = (int*)p;                             p += (size_t)N * 4;
    int* cursor = (int*)p;                          p += (size_t)N * 4;
    int* rowptr = (int*)p;                          p += ((size_t)N + 1) * 4;
    int* bsum = (int*)p;                            p += 1024;
    p = (char*)(((size_t)p + 15) & ~(size_t)15);
    unsigned short* xq = (unsigned short*)p;
    const size_t need_bf16 = (size_t)(p - (char*)d_ws) + (size_t)N * DFEAT * 2;
    const bool use_bf16 = (ws_size >= need_bf16);

    (void)hipMemsetAsync(deg, 0, (size_t)N * sizeof(int), stream);

    hist_kernel<<<1024, 256, 0, stream>>>(dst, deg, E);
    blocksum_kernel<<<nb, 256, 0, stream>>>(deg, bsum, N);
    scanb_kernel<<<1, 64, 0, stream>>>(bsum, nb, rowptr + N);
    scanfinal_kernel<<<nb, 256, 0, stream>>>(deg, bsum, rowptr, cursor,
                                             src_sorted, sh_sorted, N);
    scatter_kernel<<<1024, 256, 0, stream>>>(src, dst, (const float4*)sh, cursor,
                                             src_sorted, sh_sorted, E);
    if (use_bf16) {
        prep_kernel<<<2048, 256, 0, stream>>>(x, N, W1, W2, W3, W4, W5, Ws, Wv, wtB, xq);
        fused_kernel<<<ntiles, 256, 0, stream>>>(xq, x, (const float4*)sh_sorted,
                                                 src_sorted, rowptr, wtB,
                                                 (float*)d_out, N);
    } else {
        prep_kernel<<<2048, 256, 0, stream>>>(x, 0, W1, W2, W3, W4, W5, Ws, Wv, wtB, xq);
        agg_f32_kernel<<<2048, 256, 0, stream>>>(x, (const float4*)sh_sorted,
                                                 src_sorted, rowptr, st_all, N);
        transform_kernel<<<800, 256, 0, stream>>>(x, st_all, wtB, (float*)d_out, N);
    }
}

// Round 19
// 210.966 us; speedup vs baseline: 1.2137x; 1.1071x over previous
//
#include <hip/hip_runtime.h>

#define DFEAT 160
#define STRIDE 488   // u16 LDS row stride (480 + pad)

typedef float  f4v __attribute__((ext_vector_type(4)));
typedef short  s8v __attribute__((ext_vector_type(8)));

__device__ __constant__ float kINV3 = 0.57735026918962576451f;  // 1/sqrt(3)
__device__ __constant__ float kINV6 = 0.40824829046386301637f;  // 1/sqrt(6)
__device__ __constant__ float kC0   = 0.10206207261596575f;     // 1/sqrt(96)
__device__ __constant__ float kC1   = 0.15309310892394863f;     // sqrt(3/128)
__device__ __constant__ float kLS   = 0.125f;                   // 1/sqrt(64)
__device__ __constant__ float kLV   = 0.17677669529663687f;     // 1/sqrt(32)

#define WAVE_SYNC() do { \
    asm volatile("s_waitcnt lgkmcnt(0)" ::: "memory"); \
    __builtin_amdgcn_sched_barrier(0); \
} while (0)

#define MFMA(a, b, c) __builtin_amdgcn_mfma_f32_16x16x32_bf16((a), (b), (c), 0, 0, 0)

__device__ __forceinline__ unsigned f2bf(float f) {
    const unsigned u = __builtin_bit_cast(unsigned, f);
    const unsigned r = 0x7fffu + ((u >> 16) & 1u);
    return (u + r) >> 16;
}
__device__ __forceinline__ float bf2f(unsigned short u) {
    return __builtin_bit_cast(float, ((unsigned)u) << 16);
}

// ---------- CSR build (padded segments: deg rounded up to x4) ----------
__global__ void hist_kernel(const int* __restrict__ dst, int* __restrict__ deg, int E) {
    for (int e = blockIdx.x * blockDim.x + threadIdx.x; e < E; e += gridDim.x * blockDim.x)
        atomicAdd(&deg[dst[e]], 1);
}

__global__ __launch_bounds__(256) void blocksum_kernel(const int* __restrict__ deg,
                                                       int* __restrict__ bsum, int N) {
    __shared__ int red[256];
    const int b = blockIdx.x, t = threadIdx.x;
    const int base = b * 1024;
    int s = 0;
    for (int i = t; i < 1024; i += 256) {
        const int idx = base + i;
        if (idx < N) s += (deg[idx] + 3) & ~3;
    }
    red[t] = s;
    __syncthreads();
    for (int off = 128; off > 0; off >>= 1) {
        if (t < off) red[t] += red[t + off];
        __syncthreads();
    }
    if (t == 0) bsum[b] = red[0];
}

__global__ void scanb_kernel(int* __restrict__ bsum, int nb, int* __restrict__ rowptrN) {
    if (threadIdx.x == 0 && blockIdx.x == 0) {
        int run = 0;
        for (int i = 0; i < nb; ++i) { const int v = bsum[i]; bsum[i] = run; run += v; }
        *rowptrN = run;
    }
}

// also writes the <=3 filler slots per node (src=0, sh=0) so no big memsets needed
__global__ __launch_bounds__(256) void scanfinal_kernel(const int* __restrict__ deg,
                                                        const int* __restrict__ bsum,
                                                        int* __restrict__ rowptr,
                                                        int* __restrict__ cursor,
                                                        int* __restrict__ src_sorted,
                                                        ushort4* __restrict__ sh_sorted,
                                                        int N) {
    __shared__ int ts[256];
    const int b = blockIdx.x, t = threadIdx.x;
    const int i0 = b * 1024 + t * 4;
    int dO[4], dP[4];
    #pragma unroll
    for (int j = 0; j < 4; ++j) {
        dO[j] = (i0 + j < N) ? deg[i0 + j] : 0;
        dP[j] = (dO[j] + 3) & ~3;
    }
    ts[t] = dP[0] + dP[1] + dP[2] + dP[3];
    __syncthreads();
    for (int off = 1; off < 256; off <<= 1) {
        const int v = (t >= off) ? ts[t - off] : 0;
        __syncthreads();
        ts[t] += v;
        __syncthreads();
    }
    int ex = bsum[b] + ((t == 0) ? 0 : ts[t - 1]);
    const ushort4 z4 = make_ushort4(0, 0, 0, 0);
    #pragma unroll
    for (int j = 0; j < 4; ++j) {
        if (i0 + j < N) {
            rowptr[i0 + j] = ex;
            cursor[i0 + j] = ex;
            for (int f = ex + dO[j]; f < ex + dP[j]; ++f) {
                src_sorted[f] = 0;
                sh_sorted[f] = z4;
            }
            ex += dP[j];
        }
    }
}

// scatter into sorted streams (src 4B + sh bf16x4 8B)
__global__ void scatter_kernel(const int* __restrict__ src, const int* __restrict__ dst,
                               const float4* __restrict__ sh, int* __restrict__ cursor,
                               int* __restrict__ src_sorted, ushort4* __restrict__ sh_sorted,
                               int E) {
    for (int e = blockIdx.x * blockDim.x + threadIdx.x; e < E; e += gridDim.x * blockDim.x) {
        const int pos = atomicAdd(&cursor[dst[e]], 1);
        const float4 s4 = sh[e];
        ushort4 q;
        q.x = (unsigned short)f2bf(s4.x);
        q.y = (unsigned short)f2bf(s4.y);
        q.z = (unsigned short)f2bf(s4.z);
        q.w = (unsigned short)f2bf(s4.w);
        src_sorted[pos] = src[e];
        sh_sorted[pos] = q;
    }
}

// ---------- prep: x -> bf16 copy (dense 160-row) + pack wtB[160][480] ----------
__global__ __launch_bounds__(256) void prep_kernel(
    const float* __restrict__ x, int N,
    const float* __restrict__ W1, const float* __restrict__ W2,
    const float* __restrict__ W3, const float* __restrict__ W4,
    const float* __restrict__ W5, const float* __restrict__ Ws,
    const float* __restrict__ Wv,
    unsigned short* __restrict__ wtB, unsigned short* __restrict__ xq)
{
    const int total = 160 * 480 + N * 20;
    for (int i = blockIdx.x * 256 + threadIdx.x; i < total; i += gridDim.x * 256) {
        if (i < 160 * 480) {
            const int o = i;
            const int f = o / 480, k = o % 480;
            float v = 0.f;
            if (f < 64) {
                if (k < 64) {
                    float a = 0.f;
                    for (int m = 0; m < 64; ++m) a += W1[k * 64 + m] * Ws[m * 64 + f];
                    v = kLS * kC0 * a;
                } else if (k >= 256 && k < 288) {
                    float a = 0.f;
                    for (int m = 0; m < 64; ++m) a += W2[(k - 256) * 64 + m] * Ws[m * 64 + f];
                    v = kLS * kC0 * a;
                }
            } else {
                const int w = (f - 64) / 3, ii = (f - 64) % 3;
                if (k >= 64 + 64 * ii && k < 128 + 64 * ii) {
                    float a = 0.f;
                    const int kk = k - 64 - 64 * ii;
                    for (int m = 0; m < 32; ++m) a += W3[kk * 32 + m] * Wv[m * 32 + w];
                    v = kLV * kC1 * a;
                } else if (k >= 288 + 32 * ii && k < 320 + 32 * ii) {
                    float a = 0.f;
                    const int kk = k - 288 - 32 * ii;
                    for (int m = 0; m < 32; ++m) a += W4[kk * 32 + m] * Wv[m * 32 + w];
                    v = kLV * kC1 * a;
                } else if (k >= 384 + 32 * ii && k < 416 + 32 * ii) {
                    float a = 0.f;
                    const int kk = k - 384 - 32 * ii;
                    for (int m = 0; m < 32; ++m) a += W5[kk * 32 + m] * Wv[m * 32 + w];
                    v = kLV * kC1 * a;
                }
            }
            wtB[o] = (unsigned short)f2bf(v);
        } else {
            const int s = i - 160 * 480;   // int4 slot: 8 bf16 = 8 floats
            const float4 a = ((const float4*)x)[2 * s + 0];
            const float4 b = ((const float4*)x)[2 * s + 1];
            int4 o;
            o.x = (int)(f2bf(a.x) | (f2bf(a.y) << 16));
            o.y = (int)(f2bf(a.z) | (f2bf(a.w) << 16));
            o.z = (int)(f2bf(b.x) | (f2bf(b.y) << 16));
            o.w = (int)(f2bf(b.z) | (f2bf(b.w) << 16));
            ((int4*)xq)[s] = o;
        }
    }
}

// ---------- fused agg (LDS state) + MFMA transform: ONE 16-node tile per block ----------
__global__ __launch_bounds__(256, 8) void fused_kernel(
    const unsigned short* __restrict__ xq, const float* __restrict__ x,
    const ushort4* __restrict__ shs, const int* __restrict__ srcs,
    const int* __restrict__ rowptr, const unsigned short* __restrict__ wtB,
    float* __restrict__ out, int N)
{
    __shared__ unsigned short st[16 * STRIDE];

    const int tid  = threadIdx.x;
    const int lane = tid & 63;
    const int wid  = tid >> 6;
    const bool lo  = (lane < 32);
    const int  w   = lane & 31;
    const int  l15 = lane & 15;
    const int  pp  = lane >> 4;
    const int ntiles = (N + 15) >> 4;

    for (int tile = blockIdx.x; tile < ntiles; tile += gridDim.x) {
        const int n0 = tile << 4;

        // ===== phase 1: wave wid aggregates nodes n0+4*wid .. +3 -> st rows =====
        for (int j = 0; j < 4; ++j) {
            const int q = 4 * wid + j;
            const int n = n0 + q;
            if (n < N) {
                const int beg = rowptr[n];
                const int end = rowptr[n + 1];

                float r0 = 0.f, r1 = 0.f, r2 = 0.f, r3 = 0.f;
                float a2 = 0.f, a4x = 0.f, a4y = 0.f, a4z = 0.f;
                float a5x = 0.f, a5y = 0.f, a5z = 0.f;

#define PAIR(SA, SB, SHA, SHB) do { \
                const unsigned short* xa = xq + (size_t)(SA) * DFEAT; \
                const unsigned short* xb = xq + (size_t)(SB) * DFEAT; \
                const float xsA = bf2f(xa[lane]); \
                const float xsB = bf2f(xb[lane]); \
                const unsigned short* xh = lo ? xa : xb; \
                const float va = bf2f(xh[64 + 3 * w]); \
                const float vb = bf2f(xh[65 + 3 * w]); \
                const float vc = bf2f(xh[66 + 3 * w]); \
                const float eA0 = bf2f((SHA).x), eA1 = bf2f((SHA).y); \
                const float eA2 = bf2f((SHA).z), eA3 = bf2f((SHA).w); \
                const float eB0 = bf2f((SHB).x), eB1 = bf2f((SHB).y); \
                const float eB2 = bf2f((SHB).z), eB3 = bf2f((SHB).w); \
                r0 += eA0 * xsA;  r0 += eB0 * xsB; \
                r1 += eA1 * xsA;  r1 += eB1 * xsB; \
                r2 += eA2 * xsA;  r2 += eB2 * xsB; \
                r3 += eA3 * xsA;  r3 += eB3 * xsB; \
                const float he0  = lo ? eA0 : eB0; \
                const float he1x = lo ? eA1 : eB1; \
                const float he1y = lo ? eA2 : eB2; \
                const float he1z = lo ? eA3 : eB3; \
                a2  += va * he1x + vb * he1y + vc * he1z; \
                a4x += he0 * va;  a4y += he0 * vb;  a4z += he0 * vc; \
                a5x += vb * he1z;  a5x -= vc * he1y; \
                a5y += vc * he1x;  a5y -= va * he1z; \
                a5z += va * he1y;  a5z -= vb * he1x; \
            } while (0)

                for (int idx = beg; idx < end; idx += 4) {
                    const int4 s4 = *(const int4*)(srcs + idx);
                    const ushort4 shA = shs[idx + 0];
                    const ushort4 shB = shs[idx + 1];
                    const ushort4 shC = shs[idx + 2];
                    const ushort4 shD = shs[idx + 3];
                    PAIR(s4.x, s4.y, shA, shB);
                    PAIR(s4.z, s4.w, shC, shD);
                }
#undef PAIR

                a2  += __shfl_xor(a2, 32);
                a4x += __shfl_xor(a4x, 32);
                a4y += __shfl_xor(a4y, 32);
                a4z += __shfl_xor(a4z, 32);
                a5x += __shfl_xor(a5x, 32);
                a5y += __shfl_xor(a5y, 32);
                a5z += __shfl_xor(a5z, 32);

                unsigned short* sr = st + q * STRIDE;
                sr[lane]       = (unsigned short)f2bf(r0);
                sr[64 + lane]  = (unsigned short)f2bf(kINV3 * r1);
                sr[128 + lane] = (unsigned short)f2bf(kINV3 * r2);
                sr[192 + lane] = (unsigned short)f2bf(kINV3 * r3);
                sr[256 + lane] = (unsigned short)f2bf(kINV3 * (lo ? a2 : a4x));
                sr[320 + lane] = (unsigned short)f2bf(lo ? (kINV3 * a4y) : (kINV3 * a4z));
                sr[384 + lane] = (unsigned short)f2bf(lo ? (kINV6 * a5x) : (kINV6 * a5y));
                if (lo) sr[448 + lane] = (unsigned short)f2bf(kINV6 * a5z);
            }
        }
        __syncthreads();

        // ===== phase 2: 4 waves split the 10 feature-column tiles =====
        const unsigned short* arow = st + l15 * STRIDE + pp * 8;
        for (int t = wid; t < 10; t += 4) {
            f4v acc = (f4v){0.f, 0.f, 0.f, 0.f};
            const unsigned short* wrow = wtB + (size_t)(16 * t + l15) * 480 + pp * 8;
            if (t < 4) {  // hs rows: A1 (kc 0,1) + A2 (kc 8)
                acc = MFMA(*(const s8v*)(arow + 0 * 32), *(const s8v*)(wrow + 0 * 32), acc);
                acc = MFMA(*(const s8v*)(arow + 1 * 32), *(const s8v*)(wrow + 1 * 32), acc);
                acc = MFMA(*(const s8v*)(arow + 8 * 32), *(const s8v*)(wrow + 8 * 32), acc);
            } else {      // hv rows: A3 (kc 2..7) + A4 (9..11) + A5 (12..14)
                #pragma unroll
                for (int kc = 2; kc <= 7; ++kc)
                    acc = MFMA(*(const s8v*)(arow + kc * 32), *(const s8v*)(wrow + kc * 32), acc);
                #pragma unroll
                for (int kc = 9; kc <= 14; ++kc)
                    acc = MFMA(*(const s8v*)(arow + kc * 32), *(const s8v*)(wrow + kc * 32), acc);
            }
            // D (m89): row = node = pp*4+j, col = feat = 16t+l15
            #pragma unroll
            for (int j = 0; j < 4; ++j) {
                const int nq = n0 + pp * 4 + j;
                if (nq < N) {
                    const size_t off = (size_t)nq * DFEAT + 16 * t + l15;
                    out[off] = x[off] + fmaxf(acc[j], 0.f);
                }
            }
        }
        __syncthreads();  // st reads done before any next-tile writes
    }
}

// ---------- fp32 fallback path ----------
__global__ __launch_bounds__(256, 8) void agg_f32_kernel(
    const float* __restrict__ x, const ushort4* __restrict__ shs,
    const int* __restrict__ srcs, const int* __restrict__ rowptr,
    unsigned short* __restrict__ st_all, int N)
{
    const int tid  = threadIdx.x;
    const int lane = tid & 63;
    const int wid  = tid >> 6;
    const bool lo  = (lane < 32);
    const int  w   = lane & 31;

    for (int n = blockIdx.x * 4 + wid; n < N; n += gridDim.x * 4) {
        const int beg = rowptr[n];
        const int end = rowptr[n + 1];

        float r0 = 0.f, r1 = 0.f, r2 = 0.f, r3 = 0.f;
        float a2 = 0.f, a4x = 0.f, a4y = 0.f, a4z = 0.f;
        float a5x = 0.f, a5y = 0.f, a5z = 0.f;

#define PAIR(SA, SB, SHA, SHB) do { \
            const float* xa = x + (size_t)(SA) * DFEAT; \
            const float* xb = x + (size_t)(SB) * DFEAT; \
            const float xsA = xa[lane]; \
            const float xsB = xb[lane]; \
            const float* xh = lo ? xa : xb; \
            const float va = xh[64 + 3 * w]; \
            const float vb = xh[65 + 3 * w]; \
            const float vc = xh[66 + 3 * w]; \
            const float eA0 = bf2f((SHA).x), eA1 = bf2f((SHA).y); \
            const float eA2 = bf2f((SHA).z), eA3 = bf2f((SHA).w); \
            const float eB0 = bf2f((SHB).x), eB1 = bf2f((SHB).y); \
            const float eB2 = bf2f((SHB).z), eB3 = bf2f((SHB).w); \
            r0 += eA0 * xsA;  r0 += eB0 * xsB; \
            r1 += eA1 * xsA;  r1 += eB1 * xsB; \
            r2 += eA2 * xsA;  r2 += eB2 * xsB; \
            r3 += eA3 * xsA;  r3 += eB3 * xsB; \
            const float he0  = lo ? eA0 : eB0; \
            const float he1x = lo ? eA1 : eB1; \
            const float he1y = lo ? eA2 : eB2; \
            const float he1z = lo ? eA3 : eB3; \
            a2  += va * he1x + vb * he1y + vc * he1z; \
            a4x += he0 * va;  a4y += he0 * vb;  a4z += he0 * vc; \
            a5x += vb * he1z;  a5x -= vc * he1y; \
            a5y += vc * he1x;  a5y -= va * he1z; \
            a5z += va * he1y;  a5z -= vb * he1x; \
        } while (0)

        for (int idx = beg; idx < end; idx += 4) {
            const int4 s4 = *(const int4*)(srcs + idx);
            const ushort4 shA = shs[idx + 0];
            const ushort4 shB = shs[idx + 1];
            const ushort4 shC = shs[idx + 2];
            const ushort4 shD = shs[idx + 3];
            PAIR(s4.x, s4.y, shA, shB);
            PAIR(s4.z, s4.w, shC, shD);
        }
#undef PAIR

        a2  += __shfl_xor(a2, 32);
        a4x += __shfl_xor(a4x, 32);
        a4y += __shfl_xor(a4y, 32);
        a4z += __shfl_xor(a4z, 32);
        a5x += __shfl_xor(a5x, 32);
        a5y += __shfl_xor(a5y, 32);
        a5z += __shfl_xor(a5z, 32);

        unsigned short* sr = st_all + (size_t)n * 480;
        sr[lane]       = (unsigned short)f2bf(r0);
        sr[64 + lane]  = (unsigned short)f2bf(kINV3 * r1);
        sr[128 + lane] = (unsigned short)f2bf(kINV3 * r2);
        sr[192 + lane] = (unsigned short)f2bf(kINV3 * r3);
        sr[256 + lane] = (unsigned short)f2bf(kINV3 * (lo ? a2 : a4x));
        sr[320 + lane] = (unsigned short)f2bf(lo ? (kINV3 * a4y) : (kINV3 * a4z));
        sr[384 + lane] = (unsigned short)f2bf(lo ? (kINV6 * a5x) : (kINV6 * a5y));
        if (lo) sr[448 + lane] = (unsigned short)f2bf(kINV6 * a5z);
    }
}

__global__ __launch_bounds__(256, 4) void transform_kernel(
    const float* __restrict__ x, const unsigned short* __restrict__ st_all,
    const unsigned short* __restrict__ wtB, float* __restrict__ out, int N)
{
    __shared__ float sEp[4][16][17];
    const int tid  = threadIdx.x;
    const int lane = tid & 63;
    const int wid  = tid >> 6;
    const int l15  = lane & 15;
    const int pp   = lane >> 4;
    const int ntiles = (N + 15) >> 4;

    for (int tile = blockIdx.x * 4 + wid; tile < ntiles; tile += gridDim.x * 4) {
        const int n0 = tile * 16;
        const int nd = n0 + l15;
        const int ndc = (nd < N) ? nd : (N - 1);

        s8v a[15];
        #pragma unroll
        for (int kc = 0; kc < 15; ++kc)
            a[kc] = *(const s8v*)(st_all + (size_t)ndc * 480 + kc * 32 + pp * 8);

        for (int t = 0; t < 10; ++t) {
            f4v acc = (f4v){0.f, 0.f, 0.f, 0.f};
            const unsigned short* wrow = wtB + (size_t)(16 * t + l15) * 480 + pp * 8;
            if (t < 4) {
                acc = MFMA(a[0], *(const s8v*)(wrow + 0 * 32), acc);
                acc = MFMA(a[1], *(const s8v*)(wrow + 1 * 32), acc);
                acc = MFMA(a[8], *(const s8v*)(wrow + 8 * 32), acc);
            } else {
                #pragma unroll
                for (int kc = 2; kc <= 7; ++kc)
                    acc = MFMA(a[kc], *(const s8v*)(wrow + kc * 32), acc);
                #pragma unroll
                for (int kc = 9; kc <= 14; ++kc)
                    acc = MFMA(a[kc], *(const s8v*)(wrow + kc * 32), acc);
            }
            WAVE_SYNC();
            #pragma unroll
            for (int j = 0; j < 4; ++j)
                sEp[wid][pp * 4 + j][l15] = acc[j];
            WAVE_SYNC();
            #pragma unroll
            for (int it = 0; it < 4; ++it) {
                const int q  = it * 4 + pp;
                const int nq = n0 + q;
                if (nq < N) {
                    const float h = sEp[wid][q][l15];
                    const size_t off = (size_t)nq * DFEAT + 16 * t + l15;
                    out[off] = x[off] + fmaxf(h, 0.f);
                }
            }
        }
    }
}

extern "C" void kernel_launch(void* const* d_in, const int* in_sizes, int n_in,
                              void* d_out, int out_size, void* d_ws, size_t ws_size,
                              hipStream_t stream) {
    const float* x  = (const float*)d_in[0];
    const float* sh = (const float*)d_in[1];
    const float* W1 = (const float*)d_in[2];
    const float* W2 = (const float*)d_in[3];
    const float* W3 = (const float*)d_in[4];
    const float* W4 = (const float*)d_in[5];
    const float* W5 = (const float*)d_in[6];
    const float* Ws = (const float*)d_in[7];
    const float* Wv = (const float*)d_in[8];
    const int*   ei = (const int*)d_in[9];

    const int E = in_sizes[9] / 2;
    const int N = in_sizes[0] / DFEAT;
    const int* src = ei;
    const int* dst = ei + E;
    const int nb = (N + 1023) / 1024;
    const int ntiles = (N + 15) >> 4;
    const size_t Ep = (size_t)E + 3 * (size_t)N + 16;  // padded-edge capacity

    char* p = (char*)d_ws;
    ushort4* sh_sorted = (ushort4*)p;               p += Ep * 8;
    unsigned short* st_all = (unsigned short*)p;    p += (size_t)N * 480 * 2;  // fallback only
    unsigned short* wtB = (unsigned short*)p;       p += 160 * 480 * 2;
    int* src_sorted = (int*)p;                      p += Ep * 4;
    int* deg = (int*)p;                             p += (size_t)N * 4;
    int* cursor = (int*)p;                          p += (size_t)N * 4;
    int* rowptr = (int*)p;                          p += ((size_t)N + 1) * 4;
    int* bsum = (int*)p;                            p += 1024;
    p = (char*)(((size_t)p + 15) & ~(size_t)15);
    unsigned short* xq = (unsigned short*)p;
    const size_t need_bf16 = (size_t)(p - (char*)d_ws) + (size_t)N * DFEAT * 2;
    const bool use_bf16 = (ws_size >= need_bf16);

    (void)hipMemsetAsync(deg, 0, (size_t)N * sizeof(int), stream);

    hist_kernel<<<1024, 256, 0, stream>>>(dst, deg, E);
    blocksum_kernel<<<nb, 256, 0, stream>>>(deg, bsum, N);
    scanb_kernel<<<1, 64, 0, stream>>>(bsum, nb, rowptr + N);
    scanfinal_kernel<<<nb, 256, 0, stream>>>(deg, bsum, rowptr, cursor,
                                             src_sorted, sh_sorted, N);
    scatter_kernel<<<1024, 256, 0, stream>>>(src, dst, (const float4*)sh, cursor,
                                             src_sorted, sh_sorted, E);
    if (use_bf16) {
        prep_kernel<<<2048, 256, 0, stream>>>(x, N, W1, W2, W3, W4, W5, Ws, Wv, wtB, xq);
        fused_kernel<<<ntiles, 256, 0, stream>>>(xq, x, sh_sorted,
                                                 src_sorted, rowptr, wtB,
                                                 (float*)d_out, N);
    } else {
        prep_kernel<<<2048, 256, 0, stream>>>(x, 0, W1, W2, W3, W4, W5, Ws, Wv, wtB, xq);
        agg_f32_kernel<<<2048, 256, 0, stream>>>(x, sh_sorted,
                                                 src_sorted, rowptr, st_all, N);
        transform_kernel<<<800, 256, 0, stream>>>(x, st_all, wtB, (float*)d_out, N);
    }
}